// Round 2
// baseline (336.567 us; speedup 1.0000x reference)
//
#include <hip/hip_runtime.h>
#include <hip/hip_cooperative_groups.h>

namespace cg = cooperative_groups;

// CoAttention, R13: single cooperative kernel, 512 blocks x 256 thr, 2 grid
// syncs replace 2 kernel boundaries.
//  Phase A (bid<384): 128 E-GEMM tiles (64x64, exp fused) + 256 U/P GEMM
//                     tiles (64x64). Math identical to R12 k_projE / k_mid
//                     GEMM path. bid 384..511 idle.
//  Phase B (all 512): affinity 32x32 tiles, PAIR 2-rcp/4k, EN/ET/S1/S2.
//                     Identical to R12 aff path.
//  Phase C (all 512): final bf16 MFMA 32x32 tiles, K-chunk 128 (was 64:
//                     half the barriers), tanh epilogue. Same math.

#define NEGC (-1e12f)
#define TWO_LOG2E 2.8853900817779268f
#define LOG2E 1.4426950408889634f
#define N2LOG2E (-2.8853900817779268f)

typedef __attribute__((ext_vector_type(8))) short bf16x8;
typedef __attribute__((ext_vector_type(4))) float f32x4;

__device__ __forceinline__ short f2bf(float x)   // RNE f32->bf16
{
    union { float f; unsigned u; } v; v.f = x;
    unsigned r = (v.u + 0x7FFFu + ((v.u >> 16) & 1u)) >> 16;
    return (short)r;
}

// PAIR: acc += w.x/x0 + w.y/x1 + w.z/x2 + w.w/x3 with 2 rcp via pairing.
#define PAIR(AV, QV, WV, ACC) do {                                    \
    float x0_ = fmaf(AV.x, QV.x, 1.f);                                \
    float x1_ = fmaf(AV.y, QV.y, 1.f);                                \
    float x2_ = fmaf(AV.z, QV.z, 1.f);                                \
    float x3_ = fmaf(AV.w, QV.w, 1.f);                                \
    float r01_ = __builtin_amdgcn_rcpf(x0_ * x1_);                    \
    float r23_ = __builtin_amdgcn_rcpf(x2_ * x3_);                    \
    float z01_ = fmaf(WV.y, x0_, WV.x * x1_);                         \
    float z23_ = fmaf(WV.w, x2_, WV.z * x3_);                         \
    ACC = fmaf(r01_, z01_, ACC);                                      \
    ACC = fmaf(r23_, z23_, ACC);                                      \
} while (0)

__global__ __launch_bounds__(256, 2) void k_fused(
    const float* __restrict__ ctx1, const float* __restrict__ ctx2,
    const float* __restrict__ mask1, const float* __restrict__ mask2,
    const float* __restrict__ Wh, const float* __restrict__ bh,
    const float* __restrict__ wo,
    const float* __restrict__ W12, const float* __restrict__ b12,
    const float* __restrict__ W21, const float* __restrict__ b21,
    float* __restrict__ ws, float* __restrict__ out)
{
    // workspace layout (same as R12)
    float* E1  = ws;                 // 262144
    float* E2  = E1  + 262144;
    float* P12 = E2  + 262144;
    float* U1  = P12 + 262144;
    float* P21 = U1  + 262144;
    float* U2  = P21 + 262144;
    float* p1  = U2  + 262144;       // 1024
    float* p2  = p1  + 1024;
    float* S1  = p2  + 1024;         // 1024
    float* S2  = S1  + 1024;
    float* EN  = S2  + 1024;         // 524288
    float* ET  = EN  + 524288;       // 524288

    // LDS union: A 34816 (2x 64*136 bf16) | B 38400 (2x 32*132 f32 + 32*36)
    //          | C 19456 (2x 32*136 bf16 + 512 f32)
    __shared__ __align__(16) char smem[38400];

    const int t   = threadIdx.x;
    const int bid = blockIdx.x;

    // ---------------------------------------------------------- Phase A
    if (bid == 0) {
        for (int idx = t; idx < 1024; idx += 256) {
            int row = idx >> 1, b = idx & 1;
            p1[b * 512 + row] = __builtin_amdgcn_exp2f(LOG2E * (1.f - mask1[idx]) * NEGC);
            p2[b * 512 + row] = __builtin_amdgcn_exp2f(LOG2E * (1.f - mask2[idx]) * NEGC);
            S1[b * 512 + row] = 0.f;
            S2[b * 512 + row] = 0.f;
        }
    }

    if (bid < 384) {
        const float* A; const float* W; const float* bias; float* outp; int expm;
        int r0, n0;
        if (bid < 128) {               // E-GEMMs (aff inputs)
            const int g = bid >> 6, i6 = bid & 63;
            r0 = (i6 & 15) * 64; n0 = (i6 >> 4) * 64;
            A = g ? ctx2 : ctx1; W = g ? Wh + 65536 : Wh;
            bias = g ? 0 : bh; outp = g ? E2 : E1; expm = 1;
        } else {                       // U/P GEMMs (final inputs)
            const int idx = bid - 128;
            const int g = idx >> 6;
            r0 = (idx & 15) * 64; n0 = ((idx >> 4) & 3) * 64;
            expm = 0;
            switch (g) {
              case 0:  A = ctx2; W = W12;         bias = b12; outp = P12; break;
              case 1:  A = ctx1; W = W12 + 65536; bias = 0;   outp = U1;  break;
              case 2:  A = ctx1; W = W21;         bias = b21; outp = P21; break;
              default: A = ctx2; W = W21 + 65536; bias = 0;   outp = U2;  break;
            }
        }

        short* Abf = (short*)smem;            // [64][136]
        short* Bbf = Abf + 64 * 136;          // [64][136]

        const int w    = t >> 6;
        const int lane = t & 63;
        const int quad = lane >> 4;
        const int lr   = lane & 15;

        f32x4 acc[4] = {};

        for (int kc = 0; kc < 256; kc += 128) {
            #pragma unroll
            for (int i = 0; i < 8; ++i) {             // A: 64 rows x 128 k
                int slot = i * 256 + t;
                int r = slot >> 5, kq = (slot & 31) << 2;
                float4 v = *(const float4*)(A + (r0 + r) * 256 + kc + kq);
                short4 s; s.x = f2bf(v.x); s.y = f2bf(v.y); s.z = f2bf(v.z); s.w = f2bf(v.w);
                *(short4*)(Abf + r * 136 + kq) = s;
            }
            #pragma unroll
            for (int i = 0; i < 8; ++i) {             // B: 128 k x 64 n -> B^T
                int slot = i * 256 + t;
                int bk = slot >> 4, bn4 = (slot & 15) << 2;
                float4 v = *(const float4*)(W + (kc + bk) * 256 + n0 + bn4);
                Bbf[(bn4 + 0) * 136 + bk] = f2bf(v.x);
                Bbf[(bn4 + 1) * 136 + bk] = f2bf(v.y);
                Bbf[(bn4 + 2) * 136 + bk] = f2bf(v.z);
                Bbf[(bn4 + 3) * 136 + bk] = f2bf(v.w);
            }
            __syncthreads();
            #pragma unroll
            for (int s = 0; s < 4; ++s) {
                const int kb = s * 32 + quad * 8;
                bf16x8 a = *(const bf16x8*)(Abf + (w * 16 + lr) * 136 + kb);
                #pragma unroll
                for (int nc = 0; nc < 4; ++nc) {
                    bf16x8 b = *(const bf16x8*)(Bbf + (nc * 16 + lr) * 136 + kb);
                    acc[nc] = __builtin_amdgcn_mfma_f32_16x16x32_bf16(a, b, acc[nc], 0, 0, 0);
                }
            }
            __syncthreads();
        }

        #pragma unroll
        for (int nc = 0; nc < 4; ++nc) {
            const int col = n0 + nc * 16 + lr;
            const float bv = bias ? bias[col] : 0.f;
            #pragma unroll
            for (int reg = 0; reg < 4; ++reg) {
                int row  = r0 + w * 16 + quad * 4 + reg;   // = l*2+b
                int orow = ((row & 1) << 9) + (row >> 1);
                float v = acc[nc][reg] + bv;
                if (expm) v = __builtin_amdgcn_exp2f(v * TWO_LOG2E);
                outp[orow * 256 + col] = v;
            }
        }
    }

    __threadfence();
    cg::this_grid().sync();

    // ---------------------------------------------------------- Phase B
    {
        const int l0 = (bid & 15) * 32;
        const int m0 = ((bid >> 4) & 15) * 32;
        const int b  = bid >> 8;

        float* E1s  = (float*)smem;           // [32][132]
        float* E2s  = E1s + 32 * 132;         // [32][132]
        float* affs = E2s + 32 * 132;         // [32][36]

        const int tl = t >> 4, tm = t & 15;   // cells: l in {tl,tl+16}, m in {tm,tm+16}
        float acc[2][2] = {};

        for (int kc = 0; kc < 256; kc += 128) {
            #pragma unroll
            for (int i = 0; i < 4; ++i) {             // 32 rows x 128 k, both panels
                int slot = i * 256 + t;
                int r = slot >> 5, kq = (slot & 31) << 2;
                *(float4*)(E1s + r * 132 + kq) =
                    *(const float4*)(E1 + (((b << 9) + l0 + r) << 8) + kc + kq);
                *(float4*)(E2s + r * 132 + kq) =
                    *(const float4*)(E2 + (((b << 9) + m0 + r) << 8) + kc + kq);
            }
            __syncthreads();
            #pragma unroll 4
            for (int k0 = 0; k0 < 128; k0 += 4) {
                const float4 w  = *(const float4*)(wo + kc + k0);   // uniform -> s_load
                const float4 a0 = *(const float4*)(E1s + tl * 132 + k0);
                const float4 a1 = *(const float4*)(E1s + (tl + 16) * 132 + k0);
                const float4 q0 = *(const float4*)(E2s + tm * 132 + k0);
                const float4 q1 = *(const float4*)(E2s + (tm + 16) * 132 + k0);
                PAIR(a0, q0, w, acc[0][0]);
                PAIR(a0, q1, w, acc[0][1]);
                PAIR(a1, q0, w, acc[1][0]);
                PAIR(a1, q1, w, acc[1][1]);
            }
            __syncthreads();
        }

        // aff = -2*acc (the -2*wo factor folded); E = exp(aff), SW cancels
        affs[tl * 36 + tm]             = __builtin_amdgcn_exp2f(acc[0][0] * N2LOG2E);
        affs[tl * 36 + tm + 16]        = __builtin_amdgcn_exp2f(acc[0][1] * N2LOG2E);
        affs[(tl + 16) * 36 + tm]      = __builtin_amdgcn_exp2f(acc[1][0] * N2LOG2E);
        affs[(tl + 16) * 36 + tm + 16] = __builtin_amdgcn_exp2f(acc[1][1] * N2LOG2E);
        __syncthreads();

        const int r  = t >> 3;
        const int c4 = (t & 7) << 2;
        // natural: EN[l][m]=E*p1[l]; S1[l]+=sum_m E*p2[m]
        {
            float4 e = *(const float4*)(affs + r * 36 + c4);
            const float p1r = p1[(b << 9) + l0 + r];
            float4 vn = make_float4(e.x * p1r, e.y * p1r, e.z * p1r, e.w * p1r);
            *(float4*)(EN + (((b << 9) + l0 + r) << 9) + m0 + c4) = vn;
            float4 p2v = *(const float4*)(p2 + (b << 9) + m0 + c4);
            float s = (e.x * p2v.x + e.y * p2v.y) + (e.z * p2v.z + e.w * p2v.w);
            s += __shfl_xor(s, 1, 64);
            s += __shfl_xor(s, 2, 64);
            s += __shfl_xor(s, 4, 64);
            if ((t & 7) == 0) atomicAdd(S1 + (b << 9) + l0 + r, s);
        }
        // transposed: ET[m][l]=E^T*p2[m]; S2[m]+=sum_l E*p1[l]
        {
            float4 te;
            te.x = affs[(c4 + 0) * 36 + r];
            te.y = affs[(c4 + 1) * 36 + r];
            te.z = affs[(c4 + 2) * 36 + r];
            te.w = affs[(c4 + 3) * 36 + r];
            const float p2r = p2[(b << 9) + m0 + r];
            float4 vt = make_float4(te.x * p2r, te.y * p2r, te.z * p2r, te.w * p2r);
            *(float4*)(ET + (((b << 9) + m0 + r) << 9) + l0 + c4) = vt;
            float4 p1v = *(const float4*)(p1 + (b << 9) + l0 + c4);
            float s = (te.x * p1v.x + te.y * p1v.y) + (te.z * p1v.z + te.w * p1v.w);
            s += __shfl_xor(s, 1, 64);
            s += __shfl_xor(s, 2, 64);
            s += __shfl_xor(s, 4, 64);
            if ((t & 7) == 0) atomicAdd(S2 + (b << 9) + m0 + r, s);
        }
    }

    __threadfence();
    cg::this_grid().sync();

    // ---------------------------------------------------------- Phase C
    {
        const int r0  = (bid & 15) * 32;
        const int n0  = ((bid >> 4) & 7) * 32;
        const int z   = bid >> 7;
        const int dir = z >> 1, b = z & 1;
        const float* Ag = (dir == 0 ? ET  : EN)  + b * 262144;  // [row][k], stride 512
        const float* Sg = (dir == 0 ? S1  : S2)  + b * 512;
        const float* Bg = (dir == 0 ? U1  : U2)  + b * 131072;  // [k][n], stride 256
        const float* Pg = (dir == 0 ? P12 : P21) + b * 131072;  // [row][n], stride 256
        float* o = out + (dir == 0 ? 262144 : 0);

        short* Abf = (short*)smem;                 // [32][136] bf16, rs folded
        short* Bbf = Abf + 32 * 136;               // [32][136] bf16 (U^T)
        float* rs  = (float*)(Bbf + 32 * 136);     // [512]

        for (int i = t; i < 512; i += 256)
            rs[i] = __builtin_amdgcn_rcpf(Sg[i]);
        __syncthreads();

        const int w    = t >> 6;
        const int lane = t & 63;
        const int quad = lane >> 4;
        const int lr   = lane & 15;
        const int wr   = (w >> 1) << 4, wc = (w & 1) << 4;
        f32x4 acc = {};

        for (int kc = 0; kc < 512; kc += 128) {
            #pragma unroll
            for (int i = 0; i < 4; ++i) {           // A: 32 rows x 128 k, rs-scaled
                int slot = i * 256 + t;
                int r = slot >> 5, kq = (slot & 31) << 2;
                float4 v = *(const float4*)(Ag + ((r0 + r) << 9) + kc + kq);
                const float* rp = rs + kc + kq;
                short4 s;
                s.x = f2bf(v.x * rp[0]); s.y = f2bf(v.y * rp[1]);
                s.z = f2bf(v.z * rp[2]); s.w = f2bf(v.w * rp[3]);
                *(short4*)(Abf + r * 136 + kq) = s;
            }
            #pragma unroll
            for (int i = 0; i < 4; ++i) {           // B: 128 k x 32 n -> [n][k]
                int slot = i * 256 + t;
                int bk = slot >> 3, bn4 = (slot & 7) << 2;
                float4 v = *(const float4*)(Bg + ((kc + bk) << 8) + n0 + bn4);
                Bbf[(bn4 + 0) * 136 + bk] = f2bf(v.x);
                Bbf[(bn4 + 1) * 136 + bk] = f2bf(v.y);
                Bbf[(bn4 + 2) * 136 + bk] = f2bf(v.z);
                Bbf[(bn4 + 3) * 136 + bk] = f2bf(v.w);
            }
            __syncthreads();
            #pragma unroll
            for (int s = 0; s < 4; ++s) {
                const int kb = s * 32 + quad * 8;
                bf16x8 a  = *(const bf16x8*)(Abf + (wr + lr) * 136 + kb);
                bf16x8 bb = *(const bf16x8*)(Bbf + (wc + lr) * 136 + kb);
                acc = __builtin_amdgcn_mfma_f32_16x16x32_bf16(a, bb, acc, 0, 0, 0);
            }
            __syncthreads();
        }

        const int col = n0 + wc + lr;
        #pragma unroll
        for (int reg = 0; reg < 4; ++reg) {
            const int m = r0 + wr + quad * 4 + reg;
            float v = acc[reg] + Pg[(m << 8) + col];
            float tv = 1.f - 2.f * __builtin_amdgcn_rcpf(
                           __builtin_amdgcn_exp2f(v * TWO_LOG2E) + 1.f);
            o[((m << 1) + b) * 256 + col] = tv;
        }
    }
}

// ---------------------------------------------------------------- launch
extern "C" void kernel_launch(void* const* d_in, const int* in_sizes, int n_in,
                              void* d_out, int out_size, void* d_ws, size_t ws_size,
                              hipStream_t stream)
{
    const float* ctx1 = (const float*)d_in[0];
    const float* ctx2 = (const float*)d_in[1];
    const float* m1   = (const float*)d_in[2];
    const float* m2   = (const float*)d_in[3];
    const float* Wh   = (const float*)d_in[4];
    const float* bh   = (const float*)d_in[5];
    const float* wo   = (const float*)d_in[6];
    const float* W12  = (const float*)d_in[7];
    const float* b12  = (const float*)d_in[8];
    const float* W21  = (const float*)d_in[9];
    const float* b21  = (const float*)d_in[10];
    float* out = (float*)d_out;
    float* ws  = (float*)d_ws;

    void* args[] = { (void*)&ctx1, (void*)&ctx2, (void*)&m1, (void*)&m2,
                     (void*)&Wh, (void*)&bh, (void*)&wo,
                     (void*)&W12, (void*)&b12, (void*)&W21, (void*)&b21,
                     (void*)&ws, (void*)&out };
    hipLaunchCooperativeKernel((const void*)k_fused, dim3(512), dim3(256),
                               args, 0, stream);
}

// Round 3
// 115.261 us; speedup vs baseline: 2.9200x; 2.9200x over previous
//
#include <hip/hip_runtime.h>

// CoAttention, 3-kernel pipeline. R14 (from R12 baseline 116.75us):
//  k_projE : re-tiled 64x64/2-chunk -> 32x64/single-chunk K=256. 256 blocks
//            (was 128 = half machine idle), ONE staging latency chain per
//            block, 1 barrier round (was 4). LDS 50.7KB -> 3/CU.
//  k_mid   : VERBATIM R12 (768 blocks: 512 aff + 256 U/P GEMM, %3 interleave).
//            aff inner loop is at its 3-VALU/(l,m,k) floor.
//  k_final : K-chunk 64 -> 128 (half the barrier/drain rounds, = R13 phase C
//            staging which passed), + Pg epilogue prefetch before K-loop.
// R13 lesson: cg grid sync + per-thread threadfence = 220us of L2
// writeback/spin on 8 XCDs. Fixed overhead (fills+graph nodes) ~89us;
// controllable kernel budget only ~27us.

#define NEGC (-1e12f)
#define TWO_LOG2E 2.8853900817779268f
#define LOG2E 1.4426950408889634f
#define N2LOG2E (-2.8853900817779268f)

typedef __attribute__((ext_vector_type(8))) short bf16x8;
typedef __attribute__((ext_vector_type(4))) float f32x4;

__device__ __forceinline__ short f2bf(float x)   // RNE f32->bf16
{
    union { float f; unsigned u; } v; v.f = x;
    unsigned r = (v.u + 0x7FFFu + ((v.u >> 16) & 1u)) >> 16;
    return (short)r;
}

// --------------------------------------------------------------- k_projE
// E1 = exp(2*(ctx1 @ Wh[:256] + bh)), E2 = exp(2*(ctx2 @ Wh[256:])).
// 32x64 tile, single K=256 chunk. grid (32,4,2).
__global__ __launch_bounds__(256) void k_projE(
    const float* __restrict__ ctx1, const float* __restrict__ ctx2,
    const float* __restrict__ Wh, const float* __restrict__ bh,
    const float* __restrict__ mask1, const float* __restrict__ mask2,
    float* __restrict__ E1, float* __restrict__ E2,
    float* __restrict__ p1, float* __restrict__ p2,
    float* __restrict__ S1, float* __restrict__ S2)
{
    const int t  = threadIdx.x;
    const int g  = blockIdx.z;
    const int r0 = blockIdx.x * 32;       // rows = l*2+b in [0,1024)
    const int n0 = blockIdx.y * 64;       // N in [0,256)

    const float* A    = g ? ctx2       : ctx1;
    const float* W    = g ? Wh + 65536 : Wh;
    const float* bias = g ? 0          : bh;
    float*       outp = g ? E2         : E1;

    if (g == 0 && blockIdx.x == 0 && blockIdx.y == 0) {
        for (int idx = t; idx < 1024; idx += 256) {
            int row = idx >> 1, b = idx & 1;
            p1[b * 512 + row] = __builtin_amdgcn_exp2f(LOG2E * (1.f - mask1[idx]) * NEGC);
            p2[b * 512 + row] = __builtin_amdgcn_exp2f(LOG2E * (1.f - mask2[idx]) * NEGC);
            S1[b * 512 + row] = 0.f;
            S2[b * 512 + row] = 0.f;
        }
    }

    __shared__ __align__(16) short Abf[32 * 264];   // [m][k] bf16, full K
    __shared__ __align__(16) short Bbf[64 * 264];   // [n][k] bf16 (W^T), full K

    #pragma unroll
    for (int i = 0; i < 8; ++i) {                   // A: 32 rows x 256 k
        int slot = i * 256 + t;
        int r = slot >> 6, kq = (slot & 63) << 2;
        float4 v = *(const float4*)(A + (r0 + r) * 256 + kq);
        short4 s; s.x = f2bf(v.x); s.y = f2bf(v.y); s.z = f2bf(v.z); s.w = f2bf(v.w);
        *(short4*)(Abf + r * 264 + kq) = s;
    }
    #pragma unroll
    for (int i = 0; i < 16; ++i) {                  // B: 256 k x 64 n -> B^T
        int slot = i * 256 + t;
        int bk = slot >> 4, bn4 = (slot & 15) << 2;
        float4 v = *(const float4*)(W + bk * 256 + n0 + bn4);
        Bbf[(bn4 + 0) * 264 + bk] = f2bf(v.x);
        Bbf[(bn4 + 1) * 264 + bk] = f2bf(v.y);
        Bbf[(bn4 + 2) * 264 + bk] = f2bf(v.z);
        Bbf[(bn4 + 3) * 264 + bk] = f2bf(v.w);
    }
    __syncthreads();

    const int w    = t >> 6;
    const int lane = t & 63;
    const int quad = lane >> 4;
    const int lr   = lane & 15;
    const int h    = w & 1;               // row-half: rows r0 + h*16 + ...
    const int c    = w >> 1;              // col-half: cols n0 + c*32 + nc*16

    f32x4 acc[2] = {};

    #pragma unroll
    for (int s = 0; s < 8; ++s) {
        const int kb = s * 32 + quad * 8;
        bf16x8 a = *(const bf16x8*)(Abf + (h * 16 + lr) * 264 + kb);
        #pragma unroll
        for (int nc = 0; nc < 2; ++nc) {
            bf16x8 b = *(const bf16x8*)(Bbf + (c * 32 + nc * 16 + lr) * 264 + kb);
            acc[nc] = __builtin_amdgcn_mfma_f32_16x16x32_bf16(a, b, acc[nc], 0, 0, 0);
        }
    }

    #pragma unroll
    for (int nc = 0; nc < 2; ++nc) {
        const int col = n0 + c * 32 + nc * 16 + lr;
        const float bv = bias ? bias[col] : 0.f;
        #pragma unroll
        for (int reg = 0; reg < 4; ++reg) {
            int row  = r0 + h * 16 + quad * 4 + reg;   // = l*2+b
            int orow = ((row & 1) << 9) + (row >> 1);
            float v = acc[nc][reg] + bv;
            outp[orow * 256 + col] = __builtin_amdgcn_exp2f(v * TWO_LOG2E);
        }
    }
}

// ---------------------------------------------------------------- k_mid
// PAIR: acc += w.x/x0 + w.y/x1 + w.z/x2 + w.w/x3 with 2 rcp via pairing.
#define PAIR(AV, QV, WV, ACC) do {                                    \
    float x0_ = fmaf(AV.x, QV.x, 1.f);                                \
    float x1_ = fmaf(AV.y, QV.y, 1.f);                                \
    float x2_ = fmaf(AV.z, QV.z, 1.f);                                \
    float x3_ = fmaf(AV.w, QV.w, 1.f);                                \
    float r01_ = __builtin_amdgcn_rcpf(x0_ * x1_);                    \
    float r23_ = __builtin_amdgcn_rcpf(x2_ * x3_);                    \
    float z01_ = fmaf(WV.y, x0_, WV.x * x1_);                         \
    float z23_ = fmaf(WV.w, x2_, WV.z * x3_);                         \
    ACC = fmaf(r01_, z01_, ACC);                                      \
    ACC = fmaf(r23_, z23_, ACC);                                      \
} while (0)

__global__ __launch_bounds__(256) void k_mid(
    const float* __restrict__ ctx1, const float* __restrict__ ctx2,
    const float* __restrict__ W12, const float* __restrict__ b12,
    const float* __restrict__ W21, const float* __restrict__ b21,
    const float* __restrict__ E1g, const float* __restrict__ E2g,
    const float* __restrict__ wo,
    const float* __restrict__ p1g, const float* __restrict__ p2g,
    float* __restrict__ P12, float* __restrict__ U1,
    float* __restrict__ P21, float* __restrict__ U2,
    float* __restrict__ EN, float* __restrict__ ET,
    float* __restrict__ S1, float* __restrict__ S2)
{
    // LDS union: aff path needs 38400 B (2x 32*132 f32 + 32*36 f32);
    // gemm path needs 34816 B (2x 64*136 bf16).
    __shared__ __align__(16) char smem[38400];

    const int t   = threadIdx.x;
    const int bid = blockIdx.x;
    const int r3  = bid % 3;

    if (r3 == 2) {
        // ---------------- GEMM path: 4 U/P projections (k_final inputs only)
        const int idx = bid / 3;              // [0,256)
        const int g   = idx >> 6;             // 64 blocks per projection
        const int r0  = (idx & 15) * 64;
        const int n0  = ((idx >> 4) & 3) * 64;

        const float* A; const float* W; const float* bias; float* outp;
        switch (g) {
          case 0:  A = ctx2; W = W12;         bias = b12; outp = P12; break;
          case 1:  A = ctx1; W = W12 + 65536; bias = 0;   outp = U1;  break;
          case 2:  A = ctx1; W = W21;         bias = b21; outp = P21; break;
          default: A = ctx2; W = W21 + 65536; bias = 0;   outp = U2;  break;
        }

        short* Abf = (short*)smem;            // [64][136]
        short* Bbf = Abf + 64 * 136;          // [64][136]

        const int w    = t >> 6;
        const int lane = t & 63;
        const int quad = lane >> 4;
        const int lr   = lane & 15;

        f32x4 acc[4] = {};

        for (int kc = 0; kc < 256; kc += 128) {
            #pragma unroll
            for (int i = 0; i < 8; ++i) {             // A: 64 rows x 128 k
                int slot = i * 256 + t;
                int r = slot >> 5, kq = (slot & 31) << 2;
                float4 v = *(const float4*)(A + (r0 + r) * 256 + kc + kq);
                short4 s; s.x = f2bf(v.x); s.y = f2bf(v.y); s.z = f2bf(v.z); s.w = f2bf(v.w);
                *(short4*)(Abf + r * 136 + kq) = s;
            }
            #pragma unroll
            for (int i = 0; i < 8; ++i) {             // B: 128 k x 64 n -> B^T
                int slot = i * 256 + t;
                int bk = slot >> 4, bn4 = (slot & 15) << 2;
                float4 v = *(const float4*)(W + (kc + bk) * 256 + n0 + bn4);
                Bbf[(bn4 + 0) * 136 + bk] = f2bf(v.x);
                Bbf[(bn4 + 1) * 136 + bk] = f2bf(v.y);
                Bbf[(bn4 + 2) * 136 + bk] = f2bf(v.z);
                Bbf[(bn4 + 3) * 136 + bk] = f2bf(v.w);
            }
            __syncthreads();
            #pragma unroll
            for (int s = 0; s < 4; ++s) {
                const int kb = s * 32 + quad * 8;
                bf16x8 a = *(const bf16x8*)(Abf + (w * 16 + lr) * 136 + kb);
                #pragma unroll
                for (int nc = 0; nc < 4; ++nc) {
                    bf16x8 b = *(const bf16x8*)(Bbf + (nc * 16 + lr) * 136 + kb);
                    acc[nc] = __builtin_amdgcn_mfma_f32_16x16x32_bf16(a, b, acc[nc], 0, 0, 0);
                }
            }
            __syncthreads();
        }

        #pragma unroll
        for (int nc = 0; nc < 4; ++nc) {
            const int col = n0 + nc * 16 + lr;
            const float bv = bias ? bias[col] : 0.f;
            #pragma unroll
            for (int reg = 0; reg < 4; ++reg) {
                int row  = r0 + w * 16 + quad * 4 + reg;   // = l*2+b
                int orow = ((row & 1) << 9) + (row >> 1);
                outp[orow * 256 + col] = acc[nc][reg] + bv;
            }
        }
    } else {
        // ---------------- affinity path (identical math to R12)
        const int aidx = (bid / 3) * 2 + r3;  // [0,512)
        const int l0 = (aidx & 15) * 32;
        const int m0 = ((aidx >> 4) & 15) * 32;
        const int b  = aidx >> 8;

        float* E1s  = (float*)smem;           // [32][132]
        float* E2s  = E1s + 32 * 132;         // [32][132]
        float* affs = E2s + 32 * 132;         // [32][36]

        const int tl = t >> 4, tm = t & 15;   // cells: l in {tl,tl+16}, m in {tm,tm+16}
        float acc[2][2] = {};

        for (int kc = 0; kc < 256; kc += 128) {
            #pragma unroll
            for (int i = 0; i < 4; ++i) {             // 32 rows x 128 k, both panels
                int slot = i * 256 + t;
                int r = slot >> 5, kq = (slot & 31) << 2;
                *(float4*)(E1s + r * 132 + kq) =
                    *(const float4*)(E1g + (((b << 9) + l0 + r) << 8) + kc + kq);
                *(float4*)(E2s + r * 132 + kq) =
                    *(const float4*)(E2g + (((b << 9) + m0 + r) << 8) + kc + kq);
            }
            __syncthreads();
            #pragma unroll 4
            for (int k0 = 0; k0 < 128; k0 += 4) {
                const float4 w  = *(const float4*)(wo + kc + k0);   // uniform -> s_load
                const float4 a0 = *(const float4*)(E1s + tl * 132 + k0);
                const float4 a1 = *(const float4*)(E1s + (tl + 16) * 132 + k0);
                const float4 q0 = *(const float4*)(E2s + tm * 132 + k0);
                const float4 q1 = *(const float4*)(E2s + (tm + 16) * 132 + k0);
                PAIR(a0, q0, w, acc[0][0]);
                PAIR(a0, q1, w, acc[0][1]);
                PAIR(a1, q0, w, acc[1][0]);
                PAIR(a1, q1, w, acc[1][1]);
            }
            __syncthreads();
        }

        // aff = -2*acc (the -2*wo factor folded); E = exp(aff), SW cancels
        affs[tl * 36 + tm]             = __builtin_amdgcn_exp2f(acc[0][0] * N2LOG2E);
        affs[tl * 36 + tm + 16]        = __builtin_amdgcn_exp2f(acc[0][1] * N2LOG2E);
        affs[(tl + 16) * 36 + tm]      = __builtin_amdgcn_exp2f(acc[1][0] * N2LOG2E);
        affs[(tl + 16) * 36 + tm + 16] = __builtin_amdgcn_exp2f(acc[1][1] * N2LOG2E);
        __syncthreads();

        const int r  = t >> 3;
        const int c4 = (t & 7) << 2;
        // natural: EN[l][m]=E*p1[l]; S1[l]+=sum_m E*p2[m]
        {
            float4 e = *(const float4*)(affs + r * 36 + c4);
            const float p1r = p1g[(b << 9) + l0 + r];
            float4 vn = make_float4(e.x * p1r, e.y * p1r, e.z * p1r, e.w * p1r);
            *(float4*)(EN + (((b << 9) + l0 + r) << 9) + m0 + c4) = vn;
            float4 p2v = *(const float4*)(p2g + (b << 9) + m0 + c4);
            float s = (e.x * p2v.x + e.y * p2v.y) + (e.z * p2v.z + e.w * p2v.w);
            s += __shfl_xor(s, 1, 64);
            s += __shfl_xor(s, 2, 64);
            s += __shfl_xor(s, 4, 64);
            if ((t & 7) == 0) atomicAdd(S1 + (b << 9) + l0 + r, s);
        }
        // transposed: ET[m][l]=E^T*p2[m]; S2[m]+=sum_l E*p1[l]
        {
            float4 te;
            te.x = affs[(c4 + 0) * 36 + r];
            te.y = affs[(c4 + 1) * 36 + r];
            te.z = affs[(c4 + 2) * 36 + r];
            te.w = affs[(c4 + 3) * 36 + r];
            const float p2r = p2g[(b << 9) + m0 + r];
            float4 vt = make_float4(te.x * p2r, te.y * p2r, te.z * p2r, te.w * p2r);
            *(float4*)(ET + (((b << 9) + m0 + r) << 9) + l0 + c4) = vt;
            float4 p1v = *(const float4*)(p1g + (b << 9) + l0 + c4);
            float s = (te.x * p1v.x + te.y * p1v.y) + (te.z * p1v.z + te.w * p1v.w);
            s += __shfl_xor(s, 1, 64);
            s += __shfl_xor(s, 2, 64);
            s += __shfl_xor(s, 4, 64);
            if ((t & 7) == 0) atomicAdd(S2 + (b << 9) + m0 + r, s);
        }
    }
}

// --------------------------------------------------------------- k_final
__global__ __launch_bounds__(256) void k_final(
    const float* __restrict__ EN, const float* __restrict__ ET,
    const float* __restrict__ U1, const float* __restrict__ U2,
    const float* __restrict__ P12, const float* __restrict__ P21,
    const float* __restrict__ S1, const float* __restrict__ S2,
    float* __restrict__ out)
{
    const int t   = threadIdx.x;
    const int r0  = blockIdx.x * 32, n0 = blockIdx.y * 32;
    const int dir = blockIdx.z >> 1, b = blockIdx.z & 1;
    const float* Ag = (dir == 0 ? ET  : EN)  + b * 262144;  // [row][k], stride 512
    const float* Sg = (dir == 0 ? S1  : S2)  + b * 512;
    const float* Bg = (dir == 0 ? U1  : U2)  + b * 131072;  // [k][n], stride 256
    const float* Pg = (dir == 0 ? P12 : P21) + b * 131072;  // [row][n], stride 256
    float* o = out + (dir == 0 ? 262144 : 0);

    __shared__ __align__(16) short Abf[32 * 136];   // [row][k] bf16, rs folded
    __shared__ __align__(16) short Bbf[32 * 136];   // [n][k] bf16 (U^T)
    __shared__ __align__(16) float rs[512];

    for (int i = t; i < 512; i += 256)
        rs[i] = __builtin_amdgcn_rcpf(Sg[i]);

    const int w    = t >> 6;
    const int lane = t & 63;
    const int quad = lane >> 4;
    const int lr   = lane & 15;
    const int wr   = (w >> 1) << 4, wc = (w & 1) << 4;
    const int col  = n0 + wc + lr;

    float pre[4];                          // Pg epilogue prefetch
    #pragma unroll
    for (int reg = 0; reg < 4; ++reg) {
        const int m = r0 + wr + quad * 4 + reg;
        pre[reg] = Pg[(m << 8) + col];
    }
    __syncthreads();

    f32x4 acc = {};

    for (int kc = 0; kc < 512; kc += 128) {
        #pragma unroll
        for (int i = 0; i < 4; ++i) {               // A: 32 rows x 128 k, rs-scaled
            int slot = i * 256 + t;
            int r = slot >> 5, kq = (slot & 31) << 2;
            float4 v = *(const float4*)(Ag + ((r0 + r) << 9) + kc + kq);
            const float* rp = rs + kc + kq;
            short4 s;
            s.x = f2bf(v.x * rp[0]); s.y = f2bf(v.y * rp[1]);
            s.z = f2bf(v.z * rp[2]); s.w = f2bf(v.w * rp[3]);
            *(short4*)(Abf + r * 136 + kq) = s;
        }
        #pragma unroll
        for (int i = 0; i < 4; ++i) {               // B: 128 k x 32 n -> [n][k]
            int slot = i * 256 + t;
            int bk = slot >> 3, bn4 = (slot & 7) << 2;
            float4 v = *(const float4*)(Bg + ((kc + bk) << 8) + n0 + bn4);
            Bbf[(bn4 + 0) * 136 + bk] = f2bf(v.x);
            Bbf[(bn4 + 1) * 136 + bk] = f2bf(v.y);
            Bbf[(bn4 + 2) * 136 + bk] = f2bf(v.z);
            Bbf[(bn4 + 3) * 136 + bk] = f2bf(v.w);
        }
        __syncthreads();
        #pragma unroll
        for (int s = 0; s < 4; ++s) {
            const int kb = s * 32 + quad * 8;
            bf16x8 a  = *(const bf16x8*)(Abf + (wr + lr) * 136 + kb);
            bf16x8 bb = *(const bf16x8*)(Bbf + (wc + lr) * 136 + kb);
            acc = __builtin_amdgcn_mfma_f32_16x16x32_bf16(a, bb, acc, 0, 0, 0);
        }
        __syncthreads();
    }

    #pragma unroll
    for (int reg = 0; reg < 4; ++reg) {
        const int m = r0 + wr + quad * 4 + reg;
        float v = acc[reg] + pre[reg];
        float tv = 1.f - 2.f * __builtin_amdgcn_rcpf(
                       __builtin_amdgcn_exp2f(v * TWO_LOG2E) + 1.f);
        o[((m << 1) + b) * 256 + col] = tv;
    }
}

// ---------------------------------------------------------------- launch
extern "C" void kernel_launch(void* const* d_in, const int* in_sizes, int n_in,
                              void* d_out, int out_size, void* d_ws, size_t ws_size,
                              hipStream_t stream)
{
    const float* ctx1 = (const float*)d_in[0];
    const float* ctx2 = (const float*)d_in[1];
    const float* m1   = (const float*)d_in[2];
    const float* m2   = (const float*)d_in[3];
    const float* Wh   = (const float*)d_in[4];
    const float* bh   = (const float*)d_in[5];
    const float* wo   = (const float*)d_in[6];
    const float* W12  = (const float*)d_in[7];
    const float* b12  = (const float*)d_in[8];
    const float* W21  = (const float*)d_in[9];
    const float* b21  = (const float*)d_in[10];
    float* out = (float*)d_out;
    float* ws  = (float*)d_ws;

    float* E1  = ws;                 // 262144
    float* E2  = E1  + 262144;
    float* P12 = E2  + 262144;
    float* U1  = P12 + 262144;
    float* P21 = U1  + 262144;
    float* U2  = P21 + 262144;
    float* p1  = U2  + 262144;       // 1024
    float* p2  = p1  + 1024;
    float* S1  = p2  + 1024;         // 1024
    float* S2  = S1  + 1024;
    float* EN  = S2  + 1024;         // 524288
    float* ET  = EN  + 524288;       // 524288

    hipLaunchKernelGGL(k_projE, dim3(32, 4, 2), dim3(256), 0, stream,
                       ctx1, ctx2, Wh, bh, m1, m2, E1, E2, p1, p2, S1, S2);
    hipLaunchKernelGGL(k_mid, dim3(768, 1, 1), dim3(256), 0, stream,
                       ctx1, ctx2, W12, b12, W21, b21,
                       E1, E2, wo, p1, p2,
                       P12, U1, P21, U2, EN, ET, S1, S2);
    hipLaunchKernelGGL(k_final, dim3(16, 8, 4), dim3(256), 0, stream,
                       EN, ET, U1, U2, P12, P21, S1, S2, out);
}